// Round 1
// baseline (498.472 us; speedup 1.0000x reference)
//
#include <hip/hip_runtime.h>
#include <hip/hip_bf16.h>

typedef unsigned short u16;
typedef short bf16x8 __attribute__((ext_vector_type(8)));
typedef float f32x4 __attribute__((ext_vector_type(4)));

#define DM 1024
#define SEQ 2048
#define MTOK 8192   // 4*2048
#define NQKV 3072

__device__ __forceinline__ u16 f2bf(float f) {
  union { float f; unsigned u; } a; a.f = f;
  unsigned r = a.u + 0x7FFFu + ((a.u >> 16) & 1u);
  return (u16)(r >> 16);
}

__device__ __forceinline__ void gload_lds16(const u16* g, u16* l) {
  __builtin_amdgcn_global_load_lds(
      (const __attribute__((address_space(1))) unsigned int*)g,
      (__attribute__((address_space(3))) unsigned int*)l, 16, 0, 0);
}

// ---------------- cast x (fp32 -> bf16), vectorized ----------------
__global__ __launch_bounds__(256) void cast_x_kernel(const float* __restrict__ in,
                                                     u16* __restrict__ out) {
  int i = blockIdx.x * 256 + threadIdx.x;   // grid sized exactly: i < MTOK*DM/4
  float4 v = ((const float4*)in)[i];
  ushort4 o;
  o.x = f2bf(v.x); o.y = f2bf(v.y); o.z = f2bf(v.z); o.w = f2bf(v.w);
  ((ushort4*)out)[i] = o;
}

// ---------------- transpose + cast: in [R][C] fp32 -> out [C][R] bf16 ----------------
__global__ __launch_bounds__(256) void transpose_cast_kernel(const float* __restrict__ in,
                                                             u16* __restrict__ out,
                                                             int R, int C) {
  __shared__ float tile[32][33];
  const int tx = threadIdx.x & 31, ty = threadIdx.x >> 5;
  const int r0 = blockIdx.y << 5, c0 = blockIdx.x << 5;
#pragma unroll
  for (int i = 0; i < 32; i += 8)
    tile[ty + i][tx] = in[(size_t)(r0 + ty + i) * C + (c0 + tx)];
  __syncthreads();
#pragma unroll
  for (int i = 0; i < 32; i += 8)
    out[(size_t)(c0 + ty + i) * R + (r0 + tx)] = f2bf(tile[tx][ty + i]);
}

// ---------------- GEMM: A[M][1024] bf16 @ Bt[N][1024]^T, 128x128 tile ----------------
// EPI=0: scatter to q [bh][s][d], k [bh][s][d], vT [bh][d][s] with bias
// EPI=1: fp32 out [row][col] + bias
template <int EPI>
__global__ __launch_bounds__(256) void gemm_bt_kernel(
    const u16* __restrict__ A, const u16* __restrict__ Bt,
    const float* __restrict__ bias,
    u16* __restrict__ oq, u16* __restrict__ ok, u16* __restrict__ ovT,
    float* __restrict__ of, int N) {
  const int K = 1024;
  __shared__ alignas(16) u16 As[128 * 32];
  __shared__ alignas(16) u16 Bs[128 * 32];
  const int tid = threadIdx.x;
  const int lane = tid & 63, wid = tid >> 6;
  const int wr = wid >> 1, wc = wid & 1;
  const int l15 = lane & 15, l4 = lane >> 4;
  const int row0 = blockIdx.y << 7, col0 = blockIdx.x << 7;

  f32x4 acc[4][4];
#pragma unroll
  for (int m = 0; m < 4; ++m)
#pragma unroll
    for (int n = 0; n < 4; ++n) acc[m][n] = (f32x4){0.f, 0.f, 0.f, 0.f};

  for (int kt = 0; kt < K; kt += 32) {
    __syncthreads();
#pragma unroll
    for (int i = 0; i < 2; ++i) {
      const int tt = tid + (i << 8);
      const int r = tt >> 2, kk = (tt & 3) << 3;
      gload_lds16(A + (size_t)(row0 + r) * K + kt + kk, As + tt * 8);
      gload_lds16(Bt + (size_t)(col0 + r) * K + kt + kk, Bs + tt * 8);
    }
    __syncthreads();
    bf16x8 a[4], b[4];
#pragma unroll
    for (int m = 0; m < 4; ++m)
      a[m] = *(const bf16x8*)(As + ((wr << 6) + (m << 4) + l15) * 32 + (l4 << 3));
#pragma unroll
    for (int n = 0; n < 4; ++n)
      b[n] = *(const bf16x8*)(Bs + ((wc << 6) + (n << 4) + l15) * 32 + (l4 << 3));
#pragma unroll
    for (int m = 0; m < 4; ++m)
#pragma unroll
      for (int n = 0; n < 4; ++n)
        acc[m][n] = __builtin_amdgcn_mfma_f32_16x16x32_bf16(a[m], b[n], acc[m][n], 0, 0, 0);
  }

#pragma unroll
  for (int n = 0; n < 4; ++n) {
    const int col = col0 + (wc << 6) + (n << 4) + l15;
    const float bv = bias[col];
    if (EPI == 0) {
      const int sel = col >> 10;
      const int h = (col & 1023) >> 6;
      const int d = col & 63;
#pragma unroll
      for (int m = 0; m < 4; ++m)
#pragma unroll
        for (int r = 0; r < 4; ++r) {
          const int row = row0 + (wr << 6) + (m << 4) + (l4 << 2) + r;
          const int b = row >> 11, s = row & 2047;
          const u16 v = f2bf(acc[m][n][r] + bv);
          const int bh = (b << 4) + h;
          if (sel == 0)      oq[((size_t)bh * SEQ + s) * 64 + d] = v;
          else if (sel == 1) ok[((size_t)bh * SEQ + s) * 64 + d] = v;
          else               ovT[((size_t)bh * 64 + d) * SEQ + s] = v;
        }
    } else {
#pragma unroll
      for (int m = 0; m < 4; ++m)
#pragma unroll
        for (int r = 0; r < 4; ++r) {
          const int row = row0 + (wr << 6) + (m << 4) + (l4 << 2) + r;
          of[(size_t)row * N + col] = acc[m][n][r] + bv;
        }
    }
  }
}

// ---------------- flash attention: 4 waves x 32 q-rows, k-tile 64 ----------------
__global__ __launch_bounds__(256) void attn_kernel(const u16* __restrict__ qb,
                                                   const u16* __restrict__ kb,
                                                   const u16* __restrict__ vT,
                                                   u16* __restrict__ zb) {
  __shared__ alignas(16) u16 Plds[4][32 * 72];
  const int bh = blockIdx.y;
  const int b = bh >> 4, h = bh & 15;
  const int tid = threadIdx.x, lane = tid & 63, wid = tid >> 6;
  const int l15 = lane & 15, l4 = lane >> 4;
  const int qrow0 = (blockIdx.x << 7) + (wid << 5);
  u16* pw = &Plds[wid][0];

  const u16* qp = qb + (size_t)bh * SEQ * 64;
  const u16* kp = kb + (size_t)bh * SEQ * 64;
  const u16* vp = vT + (size_t)bh * 64 * SEQ;

  bf16x8 aq[2][2];
#pragma unroll
  for (int m = 0; m < 2; ++m)
#pragma unroll
    for (int c = 0; c < 2; ++c)
      aq[m][c] = *(const bf16x8*)(qp + (size_t)(qrow0 + (m << 4) + l15) * 64 + (c << 5) + (l4 << 3));

  f32x4 zo[2][4];
  float mrun[2][4], lrun[2][4];
#pragma unroll
  for (int m = 0; m < 2; ++m) {
#pragma unroll
    for (int d = 0; d < 4; ++d) zo[m][d] = (f32x4){0.f, 0.f, 0.f, 0.f};
#pragma unroll
    for (int r = 0; r < 4; ++r) { mrun[m][r] = -INFINITY; lrun[m][r] = 0.f; }
  }

  const int nkt = (blockIdx.x << 1) + 2;
  for (int kt = 0; kt < nkt; ++kt) {
    const int k0 = kt << 6;
    const bool active = (k0 <= qrow0 + 31);
    if (active) {
      f32x4 s[2][4];
#pragma unroll
      for (int nf = 0; nf < 4; ++nf) {
        const bf16x8 bk0 = *(const bf16x8*)(kp + (size_t)(k0 + (nf << 4) + l15) * 64 + (l4 << 3));
        const bf16x8 bk1 = *(const bf16x8*)(kp + (size_t)(k0 + (nf << 4) + l15) * 64 + 32 + (l4 << 3));
#pragma unroll
        for (int m = 0; m < 2; ++m) {
          f32x4 t = (f32x4){0.f, 0.f, 0.f, 0.f};
          t = __builtin_amdgcn_mfma_f32_16x16x32_bf16(aq[m][0], bk0, t, 0, 0, 0);
          t = __builtin_amdgcn_mfma_f32_16x16x32_bf16(aq[m][1], bk1, t, 0, 0, 0);
          s[m][nf] = t;
        }
      }
#pragma unroll
      for (int m = 0; m < 2; ++m) {
#pragma unroll
        for (int r = 0; r < 4; ++r) {
          const int qtok = qrow0 + (m << 4) + (l4 << 2) + r;
          float mx = -INFINITY;
#pragma unroll
          for (int nf = 0; nf < 4; ++nf) {
            const int ktok = k0 + (nf << 4) + l15;
            float v = s[m][nf][r] * 0.125f;
            v = (ktok <= qtok) ? v : -INFINITY;
            s[m][nf][r] = v;
            mx = fmaxf(mx, v);
          }
          mx = fmaxf(mx, __shfl_xor(mx, 1));
          mx = fmaxf(mx, __shfl_xor(mx, 2));
          mx = fmaxf(mx, __shfl_xor(mx, 4));
          mx = fmaxf(mx, __shfl_xor(mx, 8));
          const float mnew = fmaxf(mrun[m][r], mx);
          const float alpha = __expf(mrun[m][r] - mnew);
          mrun[m][r] = mnew;
          float rs = 0.f;
#pragma unroll
          for (int nf = 0; nf < 4; ++nf) {
            const float p = __expf(s[m][nf][r] - mnew);
            s[m][nf][r] = p;
            rs += p;
          }
          rs += __shfl_xor(rs, 1);
          rs += __shfl_xor(rs, 2);
          rs += __shfl_xor(rs, 4);
          rs += __shfl_xor(rs, 8);
          lrun[m][r] = lrun[m][r] * alpha + rs;
#pragma unroll
          for (int d = 0; d < 4; ++d) zo[m][d][r] *= alpha;
        }
      }
#pragma unroll
      for (int m = 0; m < 2; ++m)
#pragma unroll
        for (int nf = 0; nf < 4; ++nf)
#pragma unroll
          for (int r = 0; r < 4; ++r)
            pw[((m << 4) + (l4 << 2) + r) * 72 + (nf << 4) + l15] = f2bf(s[m][nf][r]);
    }
    __syncthreads();
    if (active) {
      bf16x8 pa[2][2];
#pragma unroll
      for (int m = 0; m < 2; ++m)
#pragma unroll
        for (int c = 0; c < 2; ++c)
          pa[m][c] = *(const bf16x8*)(pw + ((m << 4) + l15) * 72 + (c << 5) + (l4 << 3));
#pragma unroll
      for (int d = 0; d < 4; ++d) {
        const bf16x8 bv0 = *(const bf16x8*)(vp + (size_t)((d << 4) + l15) * SEQ + k0 + (l4 << 3));
        const bf16x8 bv1 = *(const bf16x8*)(vp + (size_t)((d << 4) + l15) * SEQ + k0 + 32 + (l4 << 3));
#pragma unroll
        for (int m = 0; m < 2; ++m) {
          zo[m][d] = __builtin_amdgcn_mfma_f32_16x16x32_bf16(pa[m][0], bv0, zo[m][d], 0, 0, 0);
          zo[m][d] = __builtin_amdgcn_mfma_f32_16x16x32_bf16(pa[m][1], bv1, zo[m][d], 0, 0, 0);
        }
      }
    }
    __syncthreads();
  }

#pragma unroll
  for (int m = 0; m < 2; ++m)
#pragma unroll
    for (int d = 0; d < 4; ++d)
#pragma unroll
      for (int r = 0; r < 4; ++r) {
        const int srow = qrow0 + (m << 4) + (l4 << 2) + r;
        const int dd = (d << 4) + l15;
        const float v = zo[m][d][r] / lrun[m][r];
        zb[(((size_t)b * SEQ + srow) * 16 + h) * 64 + dd] = f2bf(v);
      }
}

// ---------------- launch ----------------
extern "C" void kernel_launch(void* const* d_in, const int* in_sizes, int n_in,
                              void* d_out, int out_size, void* d_ws, size_t ws_size,
                              hipStream_t stream) {
  const float* x     = (const float*)d_in[0];
  const float* w_qkv = (const float*)d_in[1];
  const float* b_qkv = (const float*)d_in[2];
  const float* w_out = (const float*)d_in[3];
  const float* b_out = (const float*)d_in[4];
  float* out = (float*)d_out;

  char* ws = (char*)d_ws;
  u16* xb    = (u16*)ws;  ws += (size_t)MTOK * DM * 2;    // 16 MiB
  u16* wqkvT = (u16*)ws;  ws += (size_t)NQKV * DM * 2;    // 6 MiB
  u16* woutT = (u16*)ws;  ws += (size_t)DM * DM * 2;      // 2 MiB
  u16* qb    = (u16*)ws;  ws += (size_t)MTOK * DM * 2;    // 16 MiB
  u16* kb    = (u16*)ws;  ws += (size_t)MTOK * DM * 2;    // 16 MiB
  u16* vTb   = (u16*)ws;  ws += (size_t)MTOK * DM * 2;    // 16 MiB
  u16* zbuf  = (u16*)ws;  ws += (size_t)MTOK * DM * 2;    // 16 MiB

  cast_x_kernel<<<MTOK * DM / 1024, 256, 0, stream>>>(x, xb);
  transpose_cast_kernel<<<dim3(NQKV / 32, DM / 32), 256, 0, stream>>>(w_qkv, wqkvT, DM, NQKV);
  transpose_cast_kernel<<<dim3(DM / 32, DM / 32), 256, 0, stream>>>(w_out, woutT, DM, DM);

  gemm_bt_kernel<0><<<dim3(NQKV / 128, MTOK / 128), 256, 0, stream>>>(
      xb, wqkvT, b_qkv, qb, kb, vTb, nullptr, NQKV);

  attn_kernel<<<dim3(SEQ / 128, 64), 256, 0, stream>>>(qb, kb, vTb, zbuf);

  gemm_bt_kernel<1><<<dim3(DM / 128, MTOK / 128), 256, 0, stream>>>(
      zbuf, woutT, b_out, nullptr, nullptr, nullptr, out, DM);
}

// Round 2
// 256.566 us; speedup vs baseline: 1.9429x; 1.9429x over previous
//
#include <hip/hip_runtime.h>
#include <hip/hip_bf16.h>

typedef unsigned short u16;
typedef unsigned int u32;
typedef short bf16x8 __attribute__((ext_vector_type(8)));
typedef float f32x4 __attribute__((ext_vector_type(4)));

#define DM 1024
#define SEQ 2048
#define MTOK 8192   // 4*2048
#define NQKV 3072

// 0.125 * log2(e): scores land in log2 domain -> exp2f is a single v_exp_f32
#define QSCALE 0.18033688011112042f

__device__ __forceinline__ u16 f2bf(float f) {
  union { float f; unsigned u; } a; a.f = f;
  unsigned r = a.u + 0x7FFFu + ((a.u >> 16) & 1u);
  return (u16)(r >> 16);
}

__device__ __forceinline__ u32 cvt2(float a, float b) {
  __hip_bfloat162 t = __float22bfloat162_rn(make_float2(a, b));
  u32 r; __builtin_memcpy(&r, &t, 4); return r;
}

__device__ __forceinline__ void gload_lds16(const u16* g, u16* l) {
  __builtin_amdgcn_global_load_lds(
      (const __attribute__((address_space(1))) unsigned int*)g,
      (__attribute__((address_space(3))) unsigned int*)l, 16, 0, 0);
}

// ---------------- cast x (fp32 -> bf16), vectorized ----------------
__global__ __launch_bounds__(256) void cast_x_kernel(const float* __restrict__ in,
                                                     u16* __restrict__ out) {
  int i = blockIdx.x * 256 + threadIdx.x;
  float4 v = ((const float4*)in)[i];
  ushort4 o;
  o.x = f2bf(v.x); o.y = f2bf(v.y); o.z = f2bf(v.z); o.w = f2bf(v.w);
  ((ushort4*)out)[i] = o;
}

// ---------------- transpose + cast: in [R][C] fp32 -> out [C][R] bf16 ----------------
__global__ __launch_bounds__(256) void transpose_cast_kernel(const float* __restrict__ in,
                                                             u16* __restrict__ out,
                                                             int R, int C) {
  __shared__ float tile[32][33];
  const int tx = threadIdx.x & 31, ty = threadIdx.x >> 5;
  const int r0 = blockIdx.y << 5, c0 = blockIdx.x << 5;
#pragma unroll
  for (int i = 0; i < 32; i += 8)
    tile[ty + i][tx] = in[(size_t)(r0 + ty + i) * C + (c0 + tx)];
  __syncthreads();
#pragma unroll
  for (int i = 0; i < 32; i += 8)
    out[(size_t)(c0 + ty + i) * R + (r0 + tx)] = f2bf(tile[tx][ty + i]);
}

// ---------------- GEMM: A[M][1024] bf16 @ Bt[N][1024]^T, 128x128 tile ----------------
// EPI=0: scatter to q (pre-scaled by QSCALE) [bh][s][d], k [bh][s][d], vT [bh][d][s]
// EPI=1: fp32 out [row][col] + bias
template <int EPI>
__global__ __launch_bounds__(256) void gemm_bt_kernel(
    const u16* __restrict__ A, const u16* __restrict__ Bt,
    const float* __restrict__ bias,
    u16* __restrict__ oq, u16* __restrict__ ok, u16* __restrict__ ovT,
    float* __restrict__ of, int N) {
  const int K = 1024;
  __shared__ alignas(16) u16 As[128 * 32];
  __shared__ alignas(16) u16 Bs[128 * 32];
  const int tid = threadIdx.x;
  const int lane = tid & 63, wid = tid >> 6;
  const int wr = wid >> 1, wc = wid & 1;
  const int l15 = lane & 15, l4 = lane >> 4;
  const int row0 = blockIdx.y << 7, col0 = blockIdx.x << 7;

  f32x4 acc[4][4];
#pragma unroll
  for (int m = 0; m < 4; ++m)
#pragma unroll
    for (int n = 0; n < 4; ++n) acc[m][n] = (f32x4){0.f, 0.f, 0.f, 0.f};

  for (int kt = 0; kt < K; kt += 32) {
    __syncthreads();
#pragma unroll
    for (int i = 0; i < 2; ++i) {
      const int tt = tid + (i << 8);
      const int r = tt >> 2, kk = (tt & 3) << 3;
      gload_lds16(A + (size_t)(row0 + r) * K + kt + kk, As + tt * 8);
      gload_lds16(Bt + (size_t)(col0 + r) * K + kt + kk, Bs + tt * 8);
    }
    __syncthreads();
    bf16x8 a[4], b[4];
#pragma unroll
    for (int m = 0; m < 4; ++m)
      a[m] = *(const bf16x8*)(As + ((wr << 6) + (m << 4) + l15) * 32 + (l4 << 3));
#pragma unroll
    for (int n = 0; n < 4; ++n)
      b[n] = *(const bf16x8*)(Bs + ((wc << 6) + (n << 4) + l15) * 32 + (l4 << 3));
#pragma unroll
    for (int m = 0; m < 4; ++m)
#pragma unroll
      for (int n = 0; n < 4; ++n)
        acc[m][n] = __builtin_amdgcn_mfma_f32_16x16x32_bf16(a[m], b[n], acc[m][n], 0, 0, 0);
  }

#pragma unroll
  for (int n = 0; n < 4; ++n) {
    const int col = col0 + (wc << 6) + (n << 4) + l15;
    const float bv = bias[col];
    if (EPI == 0) {
      const int sel = col >> 10;
      const int h = (col & 1023) >> 6;
      const int d = col & 63;
      const float scl = (sel == 0) ? QSCALE : 1.0f;
#pragma unroll
      for (int m = 0; m < 4; ++m)
#pragma unroll
        for (int r = 0; r < 4; ++r) {
          const int row = row0 + (wr << 6) + (m << 4) + (l4 << 2) + r;
          const int b = row >> 11, s = row & 2047;
          const u16 v = f2bf((acc[m][n][r] + bv) * scl);
          const int bh = (b << 4) + h;
          if (sel == 0)      oq[((size_t)bh * SEQ + s) * 64 + d] = v;
          else if (sel == 1) ok[((size_t)bh * SEQ + s) * 64 + d] = v;
          else               ovT[((size_t)bh * 64 + d) * SEQ + s] = v;
        }
    } else {
#pragma unroll
      for (int m = 0; m < 4; ++m)
#pragma unroll
        for (int r = 0; r < 4; ++r) {
          const int row = row0 + (wr << 6) + (m << 4) + (l4 << 2) + r;
          of[(size_t)row * N + col] = acc[m][n][r] + bv;
        }
    }
  }
}

// ---------------- flash attention: 1 wave per 32 q-rows, no barriers ----------------
// Swapped layouts throughout:
//   QK: mfma(K, Q)  -> S^T[k][q], q = lane&15 (per m-half), k = nf*16 + l4*4 + r
//   PV: mfma(V^T, P)-> Z^T[d][q], q = lane&15, d = dblk*16 + l4*4 + r
// Running m/l stats live at q = lane&15 and never move across lanes.
__global__ __launch_bounds__(64) void attn_kernel(const u16* __restrict__ qb,
                                                  const u16* __restrict__ kb,
                                                  const u16* __restrict__ vT,
                                                  u16* __restrict__ zb) {
  __shared__ alignas(16) u16 pw[32 * 72];
  const int bid = blockIdx.x;
  const int bh = ((bid & 7) << 3) | ((bid >> 3) & 7);   // 8 bh per XCD bucket
  const int qi = 63 - (bid >> 6);                       // heavy q-blocks first
  const int b = bh >> 4, h = bh & 15;
  const int lane = threadIdx.x;
  const int l15 = lane & 15, l4 = lane >> 4;
  const int qrow0 = qi << 5;

  const u16* qp = qb + (size_t)bh * SEQ * 64;
  const u16* kp = kb + (size_t)bh * SEQ * 64;
  const u16* vp = vT + (size_t)bh * 64 * SEQ;

  bf16x8 aq[2][2];
#pragma unroll
  for (int m = 0; m < 2; ++m)
#pragma unroll
    for (int c = 0; c < 2; ++c)
      aq[m][c] = *(const bf16x8*)(qp + (size_t)(qrow0 + (m << 4) + l15) * 64 + (c << 5) + (l4 << 3));

  f32x4 zo[2][4];
  float mrun[2] = {-INFINITY, -INFINITY};
  float lrun[2] = {0.f, 0.f};
#pragma unroll
  for (int m = 0; m < 2; ++m)
#pragma unroll
    for (int d = 0; d < 4; ++d) zo[m][d] = (f32x4){0.f, 0.f, 0.f, 0.f};

  const int nkt = (qi >> 1) + 1;
  for (int kt = 0; kt < nkt; ++kt) {
    const int k0 = kt << 6;
    // ---- QK^T (swapped) ----
    f32x4 s[2][4];
#pragma unroll
    for (int m = 0; m < 2; ++m)
#pragma unroll
      for (int nf = 0; nf < 4; ++nf) s[m][nf] = (f32x4){0.f, 0.f, 0.f, 0.f};
#pragma unroll
    for (int nf = 0; nf < 4; ++nf) {
      const u16* krow = kp + (size_t)(k0 + (nf << 4) + l15) * 64 + (l4 << 3);
      const bf16x8 bk0 = *(const bf16x8*)(krow);
      const bf16x8 bk1 = *(const bf16x8*)(krow + 32);
#pragma unroll
      for (int m = 0; m < 2; ++m) {
        s[m][nf] = __builtin_amdgcn_mfma_f32_16x16x32_bf16(bk0, aq[m][0], s[m][nf], 0, 0, 0);
        s[m][nf] = __builtin_amdgcn_mfma_f32_16x16x32_bf16(bk1, aq[m][1], s[m][nf], 0, 0, 0);
      }
    }
    // ---- causal mask: only the diagonal (last) tile ----
    if (kt == nkt - 1) {
#pragma unroll
      for (int m = 0; m < 2; ++m) {
        const int qtok = qrow0 + (m << 4) + l15;
#pragma unroll
        for (int nf = 0; nf < 4; ++nf)
#pragma unroll
          for (int r = 0; r < 4; ++r) {
            const int ktok = k0 + (nf << 4) + (l4 << 2) + r;
            if (ktok > qtok) s[m][nf][r] = -INFINITY;
          }
      }
    }
    // ---- online softmax (stats at q = l15; 2 shfls per reduce) ----
#pragma unroll
    for (int m = 0; m < 2; ++m) {
      float mx = s[m][0][0];
#pragma unroll
      for (int nf = 0; nf < 4; ++nf)
#pragma unroll
        for (int r = 0; r < 4; ++r) mx = fmaxf(mx, s[m][nf][r]);
      mx = fmaxf(mx, __shfl_xor(mx, 16));
      mx = fmaxf(mx, __shfl_xor(mx, 32));
      if (__ballot(mx > mrun[m])) {      // exact defer: skip when max unchanged
        const float mnew = fmaxf(mrun[m], mx);
        const float alpha = exp2f(mrun[m] - mnew);
        mrun[m] = mnew;
        lrun[m] *= alpha;
#pragma unroll
        for (int d = 0; d < 4; ++d) zo[m][d] *= alpha;
      }
      float rs = 0.f;
#pragma unroll
      for (int nf = 0; nf < 4; ++nf)
#pragma unroll
        for (int r = 0; r < 4; ++r) {
          const float p = exp2f(s[m][nf][r] - mrun[m]);
          s[m][nf][r] = p;
          rs += p;
        }
      rs += __shfl_xor(rs, 16);
      rs += __shfl_xor(rs, 32);
      lrun[m] += rs;
      // packed P write: adjacent k in-lane -> v_cvt_pk + ds_write_b32
      u16* prow = pw + ((m << 4) + l15) * 72 + (l4 << 2);
#pragma unroll
      for (int nf = 0; nf < 4; ++nf) {
        *(u32*)(prow + (nf << 4))     = cvt2(s[m][nf][0], s[m][nf][1]);
        *(u32*)(prow + (nf << 4) + 2) = cvt2(s[m][nf][2], s[m][nf][3]);
      }
    }
    // ---- PV (swapped): Z^T += V^T · P^T ----
#pragma unroll
    for (int c = 0; c < 2; ++c) {
      const bf16x8 pa0 = *(const bf16x8*)(pw + l15 * 72 + (c << 5) + (l4 << 3));
      const bf16x8 pa1 = *(const bf16x8*)(pw + (16 + l15) * 72 + (c << 5) + (l4 << 3));
#pragma unroll
      for (int d = 0; d < 4; ++d) {
        const bf16x8 av = *(const bf16x8*)(vp + (size_t)((d << 4) + l15) * SEQ + k0 + (c << 5) + (l4 << 3));
        zo[0][d] = __builtin_amdgcn_mfma_f32_16x16x32_bf16(av, pa0, zo[0][d], 0, 0, 0);
        zo[1][d] = __builtin_amdgcn_mfma_f32_16x16x32_bf16(av, pa1, zo[1][d], 0, 0, 0);
      }
    }
  }

  // ---- epilogue: 4 contiguous d per lane -> 8B stores ----
#pragma unroll
  for (int m = 0; m < 2; ++m) {
    const float inv = 1.0f / lrun[m];
    const int q = qrow0 + (m << 4) + l15;
#pragma unroll
    for (int d = 0; d < 4; ++d) {
      uint2 o;
      o.x = cvt2(zo[m][d][0] * inv, zo[m][d][1] * inv);
      o.y = cvt2(zo[m][d][2] * inv, zo[m][d][3] * inv);
      *(uint2*)(zb + (((size_t)b * SEQ + q) * 16 + h) * 64 + (d << 4) + (l4 << 2)) = o;
    }
  }
}

// ---------------- launch ----------------
extern "C" void kernel_launch(void* const* d_in, const int* in_sizes, int n_in,
                              void* d_out, int out_size, void* d_ws, size_t ws_size,
                              hipStream_t stream) {
  const float* x     = (const float*)d_in[0];
  const float* w_qkv = (const float*)d_in[1];
  const float* b_qkv = (const float*)d_in[2];
  const float* w_out = (const float*)d_in[3];
  const float* b_out = (const float*)d_in[4];
  float* out = (float*)d_out;

  char* ws = (char*)d_ws;
  u16* xb    = (u16*)ws;  ws += (size_t)MTOK * DM * 2;
  u16* wqkvT = (u16*)ws;  ws += (size_t)NQKV * DM * 2;
  u16* woutT = (u16*)ws;  ws += (size_t)DM * DM * 2;
  u16* qb    = (u16*)ws;  ws += (size_t)MTOK * DM * 2;
  u16* kb    = (u16*)ws;  ws += (size_t)MTOK * DM * 2;
  u16* vTb   = (u16*)ws;  ws += (size_t)MTOK * DM * 2;
  u16* zbuf  = (u16*)ws;  ws += (size_t)MTOK * DM * 2;

  cast_x_kernel<<<MTOK * DM / 1024, 256, 0, stream>>>(x, xb);
  transpose_cast_kernel<<<dim3(NQKV / 32, DM / 32), 256, 0, stream>>>(w_qkv, wqkvT, DM, NQKV);
  transpose_cast_kernel<<<dim3(DM / 32, DM / 32), 256, 0, stream>>>(w_out, woutT, DM, DM);

  gemm_bt_kernel<0><<<dim3(NQKV / 128, MTOK / 128), 256, 0, stream>>>(
      xb, wqkvT, b_qkv, qb, kb, vTb, nullptr, NQKV);

  attn_kernel<<<4096, 64, 0, stream>>>(qb, kb, vTb, zbuf);

  gemm_bt_kernel<1><<<dim3(DM / 128, MTOK / 128), 256, 0, stream>>>(
      zbuf, woutT, b_out, nullptr, nullptr, nullptr, out, DM);
}